// Round 9
// baseline (358.491 us; speedup 1.0000x reference)
//
#include <hip/hip_runtime.h>
#include <math.h>

// Problem constants
#define N_IMG 128
#define IC 8
#define IH 128
#define IW 128
#define OC 64
#define OH 126
#define OW 126
#define NG 16
#define CPG 4          // channels per group
#define PH 31
#define PW 31
#define GN_EPS 1e-5f
#define CELLS (PH * PW)   // 961
#define HALF0 481         // cells in half 0 (half 1: 480)

// edge2: 2 consecutive output columns (ow, ow+1) x 4 channels of the 3x3
// conv for one output row. Stats-only edge work (cols 124-125 / rows
// 124-125). ow even (8B-aligned float2 loads). acc pre-init'd with signed
// bias. Weights in LDS [ic][kh][kw][ch], pre-multiplied by sgn(gn_w*scale).
__device__ __forceinline__ void edge2(const float* __restrict__ xb,
                                      const float* wlds_,
                                      int oh, int ow,
                                      float acc[2][CPG]) {
#pragma unroll 1
    for (int ic = 0; ic < IC; ic++) {
        const float* xr = xb + ic * (IH * IW) + oh * IW + ow;
        float xv[3][4];
#pragma unroll
        for (int kh = 0; kh < 3; kh++) {
            float2 a = *(const float2*)(xr + kh * IW);
            float2 b = *(const float2*)(xr + kh * IW + 2);
            xv[kh][0] = a.x; xv[kh][1] = a.y;
            xv[kh][2] = b.x; xv[kh][3] = b.y;
        }
        const float* wk = wlds_ + ic * 36;
#pragma unroll
        for (int kh = 0; kh < 3; kh++) {
            float wr[12];
#pragma unroll
            for (int t = 0; t < 12; t++) wr[t] = wk[kh * 12 + t];
#pragma unroll
            for (int ch = 0; ch < CPG; ch++) {
                float w0 = wr[0 * 4 + ch];
                float w1 = wr[1 * 4 + ch];
                float w2 = wr[2 * 4 + ch];
                acc[0][ch] = fmaf(xv[kh][0], w0,
                             fmaf(xv[kh][1], w1,
                             fmaf(xv[kh][2], w2, acc[0][ch])));
                acc[1][ch] = fmaf(xv[kh][1], w0,
                             fmaf(xv[kh][2], w1,
                             fmaf(xv[kh][3], w2, acc[1][ch])));
            }
        }
    }
}

// load6: 6 x-rows x 6 cols into a register buffer (12 vector loads).
__device__ __forceinline__ void load6(const float* __restrict__ p,
                                      float (&buf)[6][6]) {
#pragma unroll
    for (int rr = 0; rr < 6; rr++) {
        float4 f4 = *(const float4*)(p + rr * IW);
        float2 f2 = *(const float2*)(p + rr * IW + 4);
        buf[rr][0] = f4.x; buf[rr][1] = f4.y;
        buf[rr][2] = f4.z; buf[rr][3] = f4.w;
        buf[rr][4] = f2.x; buf[rr][5] = f2.y;
    }
}

// fma36: one ic's full 3x3 conv contribution for the 4x4xCPG output block.
// 576 FMAs, weights read from LDS (wk = wlds + ic*36).
__device__ __forceinline__ void fma36(const float (&xv)[6][6],
                                      const float* wk,
                                      float (&acc)[4][4][CPG]) {
#pragma unroll
    for (int kh = 0; kh < 3; kh++) {
        float wr[12];
#pragma unroll
        for (int t = 0; t < 12; t++) wr[t] = wk[kh * 12 + t];
#pragma unroll
        for (int ch = 0; ch < CPG; ch++) {
            float w0 = wr[0 * 4 + ch];
            float w1 = wr[1 * 4 + ch];
            float w2 = wr[2 * 4 + ch];
#pragma unroll
            for (int rr = 0; rr < 4; rr++) {
#pragma unroll
                for (int j = 0; j < 4; j++) {
                    acc[rr][j][ch] = fmaf(xv[rr + kh][j],     w0,
                                     fmaf(xv[rr + kh][j + 1], w1,
                                     fmaf(xv[rr + kh][j + 2], w2, acc[rr][j][ch])));
                }
            }
        }
    }
}

// PHASE 1: one block per (n, group, half). 4096 blocks (2x the old 2048):
// stats are DECOUPLED -- pm (pooled signed max) is computable before
// mean/rstd, and the final out = a2*pm + b2 is a pure per-element affine.
// Each half-block: 2 cell-rounds (481/480 cells), its 125 edge units (stats
// only), partial {sum, sumsq} -> d_ws; raw pm -> out (out IS pm-shaped).
// Rounds 6-8 lesson: ILP pipelining (prefetch/fence/dbuf) never beat the R3
// schedule at ~2 resident blocks/CU -- so raise TLP instead: default VGPR
// budget (~80, 6 blocks/CU cap) + 16 queued blocks/CU.
__launch_bounds__(256)
__global__ void conv_pool_phase1(const float* __restrict__ x,
                                 const float* __restrict__ conv_w,
                                 const float* __restrict__ conv_b,
                                 const float* __restrict__ gn_w,
                                 const float* __restrict__ gn_b,
                                 const float* __restrict__ scale,
                                 float* __restrict__ out,
                                 float* __restrict__ sums) {
    const int b = blockIdx.x;               // 0..4095
    // XCD swizzle: 4096 = 8 x 512 (bijective). XCD j gets 16 contiguous
    // images (all 32 (g,half) blocks of an image co-resident on one XCD).
    const int wid = ((b & 7) << 9) | (b >> 3);
    const int n = wid >> 5;
    const int g = (wid >> 1) & 15;
    const int h = wid & 1;
    const int tid = threadIdx.x;

    __shared__ float wlds[IC * 3 * 3 * CPG];   // 288 floats, signed
    __shared__ float red[8];                    // 4 waves x {sum, sumsq}

    for (int t = tid; t < IC * 3 * 3 * CPG; t += 256) {
        int ch = t & 3;
        int r = t >> 2;                        // ic*9 + kh*3 + kw
        int c = g * CPG + ch;
        float sg = (gn_w[c] * scale[c] >= 0.f) ? 1.f : -1.f;
        wlds[t] = conv_w[c * (IC * 9) + r] * sg;
    }
    float biasS[CPG], sgnf[CPG];
#pragma unroll
    for (int ch = 0; ch < CPG; ch++) {
        int c = g * CPG + ch;
        float sg = (gn_w[c] * scale[c] >= 0.f) ? 1.f : -1.f;
        sgnf[ch] = sg;
        biasS[ch] = conv_b[c] * sg;
    }
    __syncthreads();

    const float* xb = x + (size_t)n * (IC * IH * IW);
    const int CS = IH * IW;                    // channel stride

    const int cbase = h * HALF0;               // 0 or 481
    const int ncell = h ? (CELLS - HALF0) : HALF0;   // 481 / 480

    float s_ch[CPG];                 // per-channel signed partial sums
    float ss_ch[CPG];                // per-channel sum of squares
#pragma unroll
    for (int ch = 0; ch < CPG; ch++) { s_ch[ch] = 0.f; ss_ch[ch] = 0.f; }
    float pm[2][CPG];                // pooled signed max per owned cell
#pragma unroll
    for (int r = 0; r < 2; r++)
#pragma unroll
        for (int ch = 0; ch < CPG; ch++) pm[r][ch] = -INFINITY;

    // ---- Main: this half's pool cells, one pass ----
#pragma unroll 1
    for (int r = 0; r < 2; r++) {
        int slot = r * 256 + tid;
        if (slot < ncell) {
            int cell = cbase + slot;
            int ph = cell / PW;
            int pw = cell - ph * PW;
            const int r0 = 4 * ph;             // conv rows r0..r0+3
            const float* xcell = xb + r0 * IW + 4 * pw;

            float acc[4][4][CPG];              // [row][col][ch]
#pragma unroll
            for (int rr = 0; rr < 4; rr++)
#pragma unroll
                for (int j = 0; j < 4; j++)
#pragma unroll
                    for (int ch = 0; ch < CPG; ch++) acc[rr][j][ch] = biasS[ch];

#pragma unroll 1
            for (int ic = 0; ic < IC; ic++) {
                float xv[6][6];
                load6(xcell + ic * CS, xv);
                fma36(xv, wlds + ic * 36, acc);
            }

            // fold into stats + pool extremes (signed domain)
#pragma unroll
            for (int rr = 0; rr < 4; rr++)
#pragma unroll
                for (int j = 0; j < 4; j++)
#pragma unroll
                    for (int ch = 0; ch < CPG; ch++) {
                        float v = acc[rr][j][ch];
                        s_ch[ch] += v;
                        ss_ch[ch] = fmaf(v, v, ss_ch[ch]);
                        pm[r][ch] = fmaxf(pm[r][ch], v);
                    }
        }
    }

    // ---- Edges (stats only): 125 units per half, 1/thread ----
    //  global u in [0,250): u<124 -> right edge row u, cols 124-125;
    //  else u2=u-124: oh=124+(u2>=63), col pair (u2 mod 63)*2.
    if (tid < 125) {
        int u = h * 125 + tid;
        int oh, ow;
        if (u < 124) {
            oh = u; ow = 124;
        } else {
            int u2 = u - 124;
            int hi = (u2 >= 63) ? 1 : 0;
            oh = 124 + hi;
            ow = (u2 - 63 * hi) * 2;
        }
        float acc[2][CPG];
#pragma unroll
        for (int j = 0; j < 2; j++)
#pragma unroll
            for (int ch = 0; ch < CPG; ch++) acc[j][ch] = biasS[ch];
        edge2(xb, wlds, oh, ow, acc);
#pragma unroll
        for (int j = 0; j < 2; j++)
#pragma unroll
            for (int ch = 0; ch < CPG; ch++) {
                float v = acc[j][ch];
                s_ch[ch] += v;
                ss_ch[ch] = fmaf(v, v, ss_ch[ch]);
            }
    }

    // ---- Block reduction -> partial sums to workspace ----
    float s = sgnf[0] * s_ch[0] + sgnf[1] * s_ch[1]
            + sgnf[2] * s_ch[2] + sgnf[3] * s_ch[3];
    float ss = ss_ch[0] + ss_ch[1] + ss_ch[2] + ss_ch[3];
#pragma unroll
    for (int off = 32; off > 0; off >>= 1) {
        s  += __shfl_down(s, off, 64);
        ss += __shfl_down(ss, off, 64);
    }
    int wave = tid >> 6;
    if ((tid & 63) == 0) { red[wave] = s; red[4 + wave] = ss; }
    __syncthreads();
    if (tid == 0) {
        sums[wid * 2]     = red[0] + red[1] + red[2] + red[3];
        sums[wid * 2 + 1] = red[4] + red[5] + red[6] + red[7];
    }

    // ---- Write RAW pm to out (phase 2 applies the affine in-place) ----
#pragma unroll 1
    for (int r = 0; r < 2; r++) {
        int slot = r * 256 + tid;
        if (slot < ncell) {
            int cell = cbase + slot;
            int ph = cell / PW;
            int pw = cell - ph * PW;
#pragma unroll
            for (int ch = 0; ch < CPG; ch++) {
                int c = g * CPG + ch;
                out[(((size_t)n * OC + c) * PH + ph) * PW + pw] = pm[r][ch];
            }
        }
    }
}

// PHASE 2: in-place affine + clamp over out. mean/rstd recomputed per
// element from the two half-sums (L2-hot, trivial vs 31MB of traffic).
__launch_bounds__(256)
__global__ void finalize_phase2(const float* __restrict__ gn_w,
                                const float* __restrict__ gn_b,
                                const float* __restrict__ scale,
                                const float* __restrict__ sums,
                                float* __restrict__ out) {
    const int total = N_IMG * OC * CELLS;
    const float inv_count = 1.f / (float)(CPG * OH * OW);
    int stride = gridDim.x * 256;
    for (int i = blockIdx.x * 256 + threadIdx.x; i < total; i += stride) {
        int n = i / (OC * CELLS);
        int rem = i - n * (OC * CELLS);
        int c = rem / CELLS;
        int g = c >> 2;
        int wb = (n * 32 + g * 2) * 2;         // sums base for (n,g)
        float S  = sums[wb]     + sums[wb + 2];
        float SS = sums[wb + 1] + sums[wb + 3];
        float mean = S * inv_count;
        float var = SS * inv_count - mean * mean;
        if (var < 0.f) var = 0.f;
        float rstd = rsqrtf(var + GN_EPS);
        float gw = gn_w[c], sc = scale[c];
        float a2 = rstd * fabsf(gw * sc);
        float b2 = (gn_b[c] - mean * rstd * gw) * sc;
        float v = fmaf(a2, out[i], b2);
        out[i] = fminf(fmaxf(v, 0.f), 1.f);
    }
}

extern "C" void kernel_launch(void* const* d_in, const int* in_sizes, int n_in,
                              void* d_out, int out_size, void* d_ws, size_t ws_size,
                              hipStream_t stream) {
    const float* x      = (const float*)d_in[0];
    const float* conv_w = (const float*)d_in[1];
    const float* conv_b = (const float*)d_in[2];
    const float* gn_w   = (const float*)d_in[3];
    const float* gn_b   = (const float*)d_in[4];
    const float* scale  = (const float*)d_in[5];
    float* out = (float*)d_out;
    float* sums = (float*)d_ws;              // 4096*2 floats = 32 KB

    hipLaunchKernelGGL(conv_pool_phase1, dim3(N_IMG * NG * 2), dim3(256), 0,
                       stream, x, conv_w, conv_b, gn_w, gn_b, scale, out, sums);
    hipLaunchKernelGGL(finalize_phase2, dim3(4096), dim3(256), 0, stream,
                       gn_w, gn_b, scale, sums, out);
}